// Round 8
// baseline (142.641 us; speedup 1.0000x reference)
//
#include <hip/hip_runtime.h>
#include <hip/hip_bf16.h>

typedef __hip_bfloat16 bf16;
typedef __attribute__((ext_vector_type(8))) short short8;
typedef __attribute__((ext_vector_type(8))) __bf16 bf16x8;
typedef __attribute__((ext_vector_type(4))) float f32x4;
typedef __attribute__((ext_vector_type(16))) float f32x16;
typedef __attribute__((ext_vector_type(4))) unsigned int u32x4;
typedef __attribute__((ext_vector_type(2))) unsigned int u32x2;

// 16x16x32: C/D col = lane&15, row = (lane>>4)*4 + reg  [m89/m91]
#define MFMA16(a, b, c)                                                        \
  __builtin_amdgcn_mfma_f32_16x16x32_bf16(__builtin_bit_cast(bf16x8, (a)),     \
                                          __builtin_bit_cast(bf16x8, (b)),     \
                                          (c), 0, 0, 0)
// 32x32x16: C/D col = lane&31, row = (reg&3)+8*(reg>>2)+4*(lane>>5) [m74/m101]
#define MFMA32(a, b, c)                                                        \
  __builtin_amdgcn_mfma_f32_32x32x16_bf16(__builtin_bit_cast(bf16x8, (a)),     \
                                          __builtin_bit_cast(bf16x8, (b)),     \
                                          (c), 0, 0, 0)

// async global->LDS, 16B/lane; LDS dest = wave-uniform base + lane*16 [m97]
#define GLD16(gsrc, ldst)                                                      \
  __builtin_amdgcn_global_load_lds(                                            \
      (const __attribute__((address_space(1))) void*)(gsrc),                   \
      (__attribute__((address_space(3))) void*)(ldst), 16, 0, 0)

__device__ inline short f2bfs(float f) {
  return __builtin_bit_cast(short, __float2bfloat16(f));
}
__device__ inline unsigned pk2(float lo, float hi) {
  unsigned a = (unsigned short)__builtin_bit_cast(short, __float2bfloat16(lo));
  unsigned b = (unsigned short)__builtin_bit_cast(short, __float2bfloat16(hi));
  return a | (b << 16);
}

template <typename T> __device__ inline short8 ld8bf(const T* p);
template <> __device__ inline short8 ld8bf<bf16>(const bf16* p) {
  return *(const short8*)p;
}
template <> __device__ inline short8 ld8bf<float>(const float* p) {
  f32x4 a = *(const f32x4*)p;
  f32x4 b = *(const f32x4*)(p + 4);
  short8 r;
  r[0] = f2bfs(a[0]); r[1] = f2bfs(a[1]); r[2] = f2bfs(a[2]); r[3] = f2bfs(a[3]);
  r[4] = f2bfs(b[0]); r[5] = f2bfs(b[1]); r[6] = f2bfs(b[2]); r[7] = f2bfs(b[3]);
  return r;
}

template <typename OT> __device__ inline void st1(OT* p, float v);
template <> __device__ inline void st1<bf16>(bf16* p, float v) {
  *p = __float2bfloat16(v);
}
template <> __device__ inline void st1<float>(float* p, float v) { *p = v; }

__device__ inline unsigned int funnel16(unsigned int hi, unsigned int lo) {
  return (unsigned int)(((((unsigned long long)hi) << 32) | lo) >> 16);
}
// u[j] = v[(j + r) & 7] — rotate 8 shorts left by r, all-static indexing.
__device__ inline short8 rotl8(short8 v, int r) {
  u32x4 W = __builtin_bit_cast(u32x4, v);
  u32x4 T, U, F;
  int wr = r >> 1;
  T[0] = (wr & 1) ? W[1] : W[0];
  T[1] = (wr & 1) ? W[2] : W[1];
  T[2] = (wr & 1) ? W[3] : W[2];
  T[3] = (wr & 1) ? W[0] : W[3];
  U[0] = (wr & 2) ? T[2] : T[0];
  U[1] = (wr & 2) ? T[3] : T[1];
  U[2] = (wr & 2) ? T[0] : T[2];
  U[3] = (wr & 2) ? T[1] : T[3];
  F[0] = (r & 1) ? funnel16(U[1], U[0]) : U[0];
  F[1] = (r & 1) ? funnel16(U[2], U[1]) : U[1];
  F[2] = (r & 1) ? funnel16(U[3], U[2]) : U[2];
  F[3] = (r & 1) ? funnel16(U[0], U[3]) : U[3];
  return __builtin_bit_cast(short8, F);
}

// ---------------------------------------------------------------------------
// cvt3: fp32 -> bf16 for three arrays (x, w_qkv, w_out), 8 elems/thread.
// ---------------------------------------------------------------------------
__global__ __launch_bounds__(256) void cvt3(
    const float* __restrict__ s0, bf16* __restrict__ d0, int n0,
    const float* __restrict__ s1, bf16* __restrict__ d1, int n1,
    const float* __restrict__ s2, bf16* __restrict__ d2, int n2) {
  int i = (blockIdx.x * 256 + threadIdx.x) * 8;
  if (i < n0) {
    *(short8*)&d0[i] = ld8bf(s0 + i);
  } else if ((i -= n0) < n1) {
    *(short8*)&d1[i] = ld8bf(s1 + i);
  } else if ((i -= n1) < n2) {
    *(short8*)&d2[i] = ld8bf(s2 + i);
  }
}

// ---------------------------------------------------------------------------
// FAST GEMM (m97 structure): all-bf16 operands, global_load_lds width-16,
// 128x128 tile, BK=64, 256 thr (2x2 waves, 64x64/wave), fp32 accum.
// ---------------------------------------------------------------------------
template <typename OT>
__global__ __launch_bounds__(256, 2) void gemm_lds_bias(
    const bf16* __restrict__ A, const bf16* __restrict__ B,
    const float* __restrict__ bias, OT* __restrict__ C, int M, int N, int K) {
  __shared__ bf16 As[128][64];
  __shared__ bf16 Bs[128][64];

  const int tid = threadIdx.x;
  const int w = tid >> 6, l = tid & 63;
  const int wr = w >> 1, wc = w & 1;
  const int m0 = blockIdx.y * 128, n0 = blockIdx.x * 128;

  f32x4 acc[4][4] = {};

  const int srow = l >> 3;
  const int scol = (l & 7) * 8;

  for (int kt = 0; kt < K; kt += 64) {
#pragma unroll
    for (int j = 0; j < 4; ++j) {
      int chunk = w * 4 + j;
      int row = chunk * 8 + srow;
      GLD16(A + (size_t)(m0 + row) * K + kt + scol, &As[0][0] + chunk * 512);
      GLD16(B + (size_t)(n0 + row) * K + kt + scol, &Bs[0][0] + chunk * 512);
    }
    __syncthreads();

#pragma unroll
    for (int kk = 0; kk < 2; ++kk) {
      short8 af[4], bfv[4];
#pragma unroll
      for (int i = 0; i < 4; ++i) {
        af[i]  = *(const short8*)&As[wr * 64 + i * 16 + (l & 15)]
                                   [kk * 32 + (l >> 4) * 8];
        bfv[i] = *(const short8*)&Bs[wc * 64 + i * 16 + (l & 15)]
                                   [kk * 32 + (l >> 4) * 8];
      }
#pragma unroll
      for (int i = 0; i < 4; ++i)
#pragma unroll
        for (int jn = 0; jn < 4; ++jn)
          acc[i][jn] = MFMA16(af[i], bfv[jn], acc[i][jn]);
    }
    __syncthreads();
  }

#pragma unroll
  for (int i = 0; i < 4; ++i) {
    int rbase = m0 + wr * 64 + i * 16 + (l >> 4) * 4;
#pragma unroll
    for (int jn = 0; jn < 4; ++jn) {
      int col = n0 + wc * 64 + jn * 16 + (l & 15);
      float bv = bias[col];
#pragma unroll
      for (int r = 0; r < 4; ++r)
        st1(&C[(size_t)(rbase + r) * N + col], acc[i][jn][r] + bv);
    }
  }
}

// ---------------------------------------------------------------------------
// FALLBACK GEMM (reg-staged, fp32/bf16 template) — used if ws too small.
// ---------------------------------------------------------------------------
template <typename AT, typename OT>
__global__ __launch_bounds__(256, 2) void gemm_bt_bias(
    const AT* __restrict__ A, const float* __restrict__ B,
    const float* __restrict__ bias, OT* __restrict__ C, int M, int N, int K) {
  __shared__ bf16 As[128][64];
  __shared__ bf16 Bs[128][64];

  const int tid = threadIdx.x;
  const int w = tid >> 6, l = tid & 63;
  const int wr = w >> 1, wc = w & 1;
  const int m0 = blockIdx.y * 128, n0 = blockIdx.x * 128;

  f32x4 acc[4][4] = {};

  const int srow = tid >> 3;
  const int scol = (tid & 7) * 8;

  for (int kt = 0; kt < K; kt += 64) {
    short8 aReg[4], bReg[4];
#pragma unroll
    for (int p = 0; p < 4; ++p) {
      int row = p * 32 + srow;
      aReg[p] = ld8bf(A + (size_t)(m0 + row) * K + kt + scol);
      bReg[p] = ld8bf(B + (size_t)(n0 + row) * K + kt + scol);
    }
    __syncthreads();
#pragma unroll
    for (int p = 0; p < 4; ++p) {
      int row = p * 32 + srow;
      *(short8*)&As[row][scol] = aReg[p];
      *(short8*)&Bs[row][scol] = bReg[p];
    }
    __syncthreads();

#pragma unroll
    for (int kk = 0; kk < 2; ++kk) {
      short8 af[4], bfv[4];
#pragma unroll
      for (int i = 0; i < 4; ++i) {
        af[i]  = *(const short8*)&As[wr * 64 + i * 16 + (l & 15)]
                                   [kk * 32 + (l >> 4) * 8];
        bfv[i] = *(const short8*)&Bs[wc * 64 + i * 16 + (l & 15)]
                                   [kk * 32 + (l >> 4) * 8];
      }
#pragma unroll
      for (int i = 0; i < 4; ++i)
#pragma unroll
        for (int jn = 0; jn < 4; ++jn)
          acc[i][jn] = MFMA16(af[i], bfv[jn], acc[i][jn]);
    }
  }

#pragma unroll
  for (int i = 0; i < 4; ++i) {
    int rbase = m0 + wr * 64 + i * 16 + (l >> 4) * 4;
#pragma unroll
    for (int jn = 0; jn < 4; ++jn) {
      int col = n0 + wc * 64 + jn * 16 + (l & 15);
      float bv = bias[col];
#pragma unroll
      for (int r = 0; r < 4; ++r)
        st1(&C[(size_t)(rbase + r) * N + col], acc[i][jn][r] + bv);
    }
  }
}

// ---------------------------------------------------------------------------
// Flash attention, swapped-operand 32x32 MFMA, double-buffered K/V LDS:
// ONE barrier per KV tile; stage-writes and global prefetch overlap compute.
// ---------------------------------------------------------------------------
__global__ __launch_bounds__(256, 2) void attn_fwd(
    const bf16* __restrict__ qkv, bf16* __restrict__ attended) {
  const int S = 2048, D3 = 3072, D = 1024;
  // bijective XCD swizzle (512 blocks = 8 XCDs x 64): each XCD owns 4 bh
  // values entirely -> K/V working set ~2 MB/XCD stays L2-resident.
  const int flat = blockIdx.y * 16 + blockIdx.x;
  const int n = (flat & 7) * 64 + (flat >> 3);
  const int qt = n & 15, bh = n >> 4;
  const int b = bh >> 4, h = bh & 15;
  const int tid = threadIdx.x, w = tid >> 6, l = tid & 63;
  const int lo5 = l & 31, hi = l >> 5;

  __shared__ bf16 K2[2][64][72];  // 18.4 KB, K[kv][e]
  __shared__ bf16 V2[2][64][72];  // 18.4 KB, V^T[e][kv]

  const int q0w = qt * 128 + w * 32;

  short8 qf[4];
  {
    size_t qrow = (size_t)(b * S + q0w + lo5) * D3 + h * 64;
#pragma unroll
    for (int ks = 0; ks < 4; ++ks)
      qf[ks] = *(const short8*)&qkv[qrow + ks * 16 + hi * 8];
  }

  float m_raw = -1e30f, l_i = 0.f;
  f32x16 o0 = {}, o1 = {};

  const float Cs = 0.125f * 1.44269504088896340736f;  // hd^-0.5 * log2(e)

  const int srow = tid >> 2;   // staged kv row
  const int scq = tid & 3;     // col chunk
  const size_t gstep = (size_t)(b * S + srow) * D3 + h * 64 + scq * 16;

  short8 k0, k1, v0, v1;
  // prologue: tile 0 -> regs -> buf0; tile 1 -> regs
  {
    const bf16* g = qkv + gstep;
    k0 = *(const short8*)&g[1024];
    k1 = *(const short8*)&g[1024 + 8];
    v0 = *(const short8*)&g[2048];
    v1 = *(const short8*)&g[2048 + 8];
  }
  *(short8*)&K2[0][srow][scq * 16] = k0;
  *(short8*)&K2[0][srow][scq * 16 + 8] = k1;
#pragma unroll
  for (int g = 0; g < 2; ++g) {
    int sI = scq * 2 + g;
    short8 u = rotl8(g ? v1 : v0, sI);
#pragma unroll
    for (int j = 0; j < 8; ++j) {
      int jj = (j + sI) & 7;
      *(short*)&V2[0][sI * 8 + jj][srow] = (short)u[j];
    }
  }
  {
    const bf16* g = qkv + gstep + (size_t)64 * D3;
    k0 = *(const short8*)&g[1024];
    k1 = *(const short8*)&g[1024 + 8];
    v0 = *(const short8*)&g[2048];
    v1 = *(const short8*)&g[2048 + 8];
  }

  for (int t = 0; t < 32; ++t) {
    const int cur = t & 1;
    __syncthreads();  // buf[cur] ready; prior reads of buf[cur^1] done

    if (t + 1 < 32) {
      // stage tile t+1 into buf[cur^1] (overlaps compute below)
      *(short8*)&K2[cur ^ 1][srow][scq * 16] = k0;
      *(short8*)&K2[cur ^ 1][srow][scq * 16 + 8] = k1;
#pragma unroll
      for (int g = 0; g < 2; ++g) {
        int sI = scq * 2 + g;
        short8 u = rotl8(g ? v1 : v0, sI);
#pragma unroll
        for (int j = 0; j < 8; ++j) {
          int jj = (j + sI) & 7;
          *(short*)&V2[cur ^ 1][sI * 8 + jj][srow] = (short)u[j];
        }
      }
      if (t + 2 < 32) {  // prefetch tile t+2 -> regs
        const bf16* g = qkv + gstep + (size_t)(t + 2) * 64 * D3;
        k0 = *(const short8*)&g[1024];
        k1 = *(const short8*)&g[1024 + 8];
        v0 = *(const short8*)&g[2048];
        v1 = *(const short8*)&g[2048 + 8];
      }
    }

    // S^T = K @ Q^T
    f32x16 s0 = {}, s1 = {};
    __builtin_amdgcn_s_setprio(1);
#pragma unroll
    for (int ks = 0; ks < 4; ++ks) {
      short8 ka0 = *(const short8*)&K2[cur][lo5][ks * 16 + hi * 8];
      short8 ka1 = *(const short8*)&K2[cur][32 + lo5][ks * 16 + hi * 8];
      s0 = MFMA32(ka0, qf[ks], s0);
      s1 = MFMA32(ka1, qf[ks], s1);
    }
    __builtin_amdgcn_s_setprio(0);

    // per-lane online softmax with defer-max (T13, THR=8 exp2-domain)
    f32x16 tm;
#pragma unroll
    for (int r = 0; r < 16; ++r) tm[r] = fmaxf(s0[r], s1[r]);
#pragma unroll
    for (int st = 8; st > 0; st >>= 1)
#pragma unroll
      for (int r = 0; r < st; ++r) tm[r] = fmaxf(tm[r], tm[r + st]);
    float mx = fmaxf(tm[0], __shfl_xor(tm[0], 32));

    bool deferred = __all((mx - m_raw) * Cs <= 8.0f);
    float mn, alpha;
    if (deferred) {
      mn = m_raw;
      alpha = 1.0f;
    } else {
      mn = fmaxf(m_raw, mx);
      alpha = __builtin_amdgcn_exp2f((m_raw - mn) * Cs);
      m_raw = mn;
    }
    float pc = mn * Cs;

    f32x16 e0, e1;
#pragma unroll
    for (int r = 0; r < 16; ++r) {
      e0[r] = __builtin_amdgcn_exp2f(__builtin_fmaf(s0[r], Cs, -pc));
      e1[r] = __builtin_amdgcn_exp2f(__builtin_fmaf(s1[r], Cs, -pc));
    }
    f32x16 ts;
#pragma unroll
    for (int r = 0; r < 16; ++r) ts[r] = e0[r] + e1[r];
#pragma unroll
    for (int st = 8; st > 0; st >>= 1)
#pragma unroll
      for (int r = 0; r < st; ++r) ts[r] += ts[r + st];
    float sf = ts[0] + __shfl_xor(ts[0], 32);
    if (deferred) {
      l_i += sf;
    } else {
      l_i = l_i * alpha + sf;
      o0 *= alpha;
      o1 *= alpha;
    }

    // pack P quads + partner-lane exchange (1 shfl per u32 pair)
    unsigned po[2][4][2];
#pragma unroll
    for (int tq = 0; tq < 4; ++tq) {
      po[0][tq][0] = pk2(e0[4 * tq], e0[4 * tq + 1]);
      po[0][tq][1] = pk2(e0[4 * tq + 2], e0[4 * tq + 3]);
      po[1][tq][0] = pk2(e1[4 * tq], e1[4 * tq + 1]);
      po[1][tq][1] = pk2(e1[4 * tq + 2], e1[4 * tq + 3]);
    }
    unsigned pr[2][2][2];
#pragma unroll
    for (int g = 0; g < 2; ++g)
#pragma unroll
      for (int p = 0; p < 2; ++p)
#pragma unroll
        for (int hf = 0; hf < 2; ++hf) {
          unsigned y = hi ? po[g][2 * p][hf] : po[g][2 * p + 1][hf];
          pr[g][p][hf] = (unsigned)__shfl_xor((int)y, 32);
        }

    // O^T += V^T @ P^T
    __builtin_amdgcn_s_setprio(1);
#pragma unroll
    for (int ks = 0; ks < 4; ++ks) {
      const int g = ks >> 1, p = ks & 1;
      u32x4 fw;
      fw[0] = hi ? pr[g][p][0] : po[g][2 * p][0];
      fw[1] = hi ? pr[g][p][1] : po[g][2 * p][1];
      fw[2] = hi ? po[g][2 * p + 1][0] : pr[g][p][0];
      fw[3] = hi ? po[g][2 * p + 1][1] : pr[g][p][1];
      short8 pf = __builtin_bit_cast(short8, fw);
      short8 va0 = *(const short8*)&V2[cur][lo5][ks * 16 + hi * 8];
      short8 va1 = *(const short8*)&V2[cur][32 + lo5][ks * 16 + hi * 8];
      o0 = MFMA32(va0, pf, o0);
      o1 = MFMA32(va1, pf, o1);
    }
    __builtin_amdgcn_s_setprio(0);
  }

  float inv = 1.0f / l_i;
  size_t orow = (size_t)(b * S + q0w + lo5) * D + h * 64;
#pragma unroll
  for (int t = 0; t < 4; ++t) {
    u32x2 w0, w1;
    w0[0] = pk2(o0[4 * t] * inv, o0[4 * t + 1] * inv);
    w0[1] = pk2(o0[4 * t + 2] * inv, o0[4 * t + 3] * inv);
    w1[0] = pk2(o1[4 * t] * inv, o1[4 * t + 1] * inv);
    w1[1] = pk2(o1[4 * t + 2] * inv, o1[4 * t + 3] * inv);
    *(u32x2*)&attended[orow + 8 * t + 4 * hi] = w0;
    *(u32x2*)&attended[orow + 32 + 8 * t + 4 * hi] = w1;
  }
}

// ---------------------------------------------------------------------------
extern "C" void kernel_launch(void* const* d_in, const int* in_sizes, int n_in,
                              void* d_out, int out_size, void* d_ws,
                              size_t ws_size, hipStream_t stream) {
  const float* x     = (const float*)d_in[0];   // [2,2048,1024] fp32
  const float* w_qkv = (const float*)d_in[1];   // [3072,1024]   fp32
  const float* b_qkv = (const float*)d_in[2];   // [3072]        fp32
  const float* w_out = (const float*)d_in[3];   // [1024,1024]   fp32
  const float* b_out = (const float*)d_in[4];   // [1024]        fp32
  float* out = (float*)d_out;                   // [2,2048,1024] fp32

  const int BS = 4096;   // B*S
  const int D = 1024, D3 = 3072;
  const int NX = BS * D, NWQ = D3 * D, NWO = D * D;

  bf16* qkv = (bf16*)d_ws;                       // [4096][3072] 25.2 MB
  bf16* att = qkv + (size_t)BS * D3;             // [4096][1024]  8.4 MB

  const size_t NEED = ((size_t)BS * D3 + (size_t)BS * D + (size_t)D3 * D +
                       (size_t)D * D) * sizeof(bf16);

  if (ws_size >= NEED) {
    bf16* xb  = att;                             // overlaid with att
    bf16* wqb = xb + (size_t)NX;
    bf16* wob = wqb + (size_t)NWQ;

    int ncvt = (NX + NWQ + NWO) / 8;
    cvt3<<<(ncvt + 255) / 256, 256, 0, stream>>>(x, xb, NX, w_qkv, wqb, NWQ,
                                                 w_out, wob, NWO);
    gemm_lds_bias<bf16><<<dim3(D3 / 128, BS / 128), 256, 0, stream>>>(
        xb, wqb, b_qkv, qkv, BS, D3, D);
    attn_fwd<<<dim3(16, 32), 256, 0, stream>>>(qkv, att);  // clobbers xb/wqb
    gemm_lds_bias<float><<<dim3(D / 128, BS / 128), 256, 0, stream>>>(
        att, wob, b_out, out, BS, D, D);
  } else {
    gemm_bt_bias<float, bf16><<<dim3(D3 / 128, BS / 128), 256, 0, stream>>>(
        x, w_qkv, b_qkv, qkv, BS, D3, D);
    attn_fwd<<<dim3(16, 32), 256, 0, stream>>>(qkv, att);
    gemm_bt_bias<bf16, float><<<dim3(D / 128, BS / 128), 256, 0, stream>>>(
        att, w_out, b_out, out, BS, D, D);
  }
}

// Round 9
// 127.271 us; speedup vs baseline: 1.1208x; 1.1208x over previous
//
#include <hip/hip_runtime.h>
#include <hip/hip_bf16.h>

typedef __hip_bfloat16 bf16;
typedef __attribute__((ext_vector_type(8))) short short8;
typedef __attribute__((ext_vector_type(8))) __bf16 bf16x8;
typedef __attribute__((ext_vector_type(4))) float f32x4;
typedef __attribute__((ext_vector_type(16))) float f32x16;
typedef __attribute__((ext_vector_type(4))) unsigned int u32x4;
typedef __attribute__((ext_vector_type(2))) unsigned int u32x2;

// 16x16x32: C/D col = lane&15, row = (lane>>4)*4 + reg  [m89/m91]
#define MFMA16(a, b, c)                                                        \
  __builtin_amdgcn_mfma_f32_16x16x32_bf16(__builtin_bit_cast(bf16x8, (a)),     \
                                          __builtin_bit_cast(bf16x8, (b)),     \
                                          (c), 0, 0, 0)
// 32x32x16: C/D col = lane&31, row = (reg&3)+8*(reg>>2)+4*(lane>>5) [m74/m101]
#define MFMA32(a, b, c)                                                        \
  __builtin_amdgcn_mfma_f32_32x32x16_bf16(__builtin_bit_cast(bf16x8, (a)),     \
                                          __builtin_bit_cast(bf16x8, (b)),     \
                                          (c), 0, 0, 0)

// async global->LDS, 16B/lane; LDS dest = wave-uniform base + lane*16 [m97]
#define GLD16(gsrc, ldst)                                                      \
  __builtin_amdgcn_global_load_lds(                                            \
      (const __attribute__((address_space(1))) void*)(gsrc),                   \
      (__attribute__((address_space(3))) void*)(ldst), 16, 0, 0)

__device__ inline short f2bfs(float f) {
  return __builtin_bit_cast(short, __float2bfloat16(f));
}
__device__ inline unsigned pk2(float lo, float hi) {
  unsigned a = (unsigned short)__builtin_bit_cast(short, __float2bfloat16(lo));
  unsigned b = (unsigned short)__builtin_bit_cast(short, __float2bfloat16(hi));
  return a | (b << 16);
}

template <typename T> __device__ inline short8 ld8bf(const T* p);
template <> __device__ inline short8 ld8bf<bf16>(const bf16* p) {
  return *(const short8*)p;
}
template <> __device__ inline short8 ld8bf<float>(const float* p) {
  f32x4 a = *(const f32x4*)p;
  f32x4 b = *(const f32x4*)(p + 4);
  short8 r;
  r[0] = f2bfs(a[0]); r[1] = f2bfs(a[1]); r[2] = f2bfs(a[2]); r[3] = f2bfs(a[3]);
  r[4] = f2bfs(b[0]); r[5] = f2bfs(b[1]); r[6] = f2bfs(b[2]); r[7] = f2bfs(b[3]);
  return r;
}

template <typename OT> __device__ inline void st1(OT* p, float v);
template <> __device__ inline void st1<bf16>(bf16* p, float v) {
  *p = __float2bfloat16(v);
}
template <> __device__ inline void st1<float>(float* p, float v) { *p = v; }

__device__ inline unsigned int funnel16(unsigned int hi, unsigned int lo) {
  return (unsigned int)(((((unsigned long long)hi) << 32) | lo) >> 16);
}
// u[j] = v[(j + r) & 7] — rotate 8 shorts left by r, all-static indexing.
__device__ inline short8 rotl8(short8 v, int r) {
  u32x4 W = __builtin_bit_cast(u32x4, v);
  u32x4 T, U, F;
  int wr = r >> 1;
  T[0] = (wr & 1) ? W[1] : W[0];
  T[1] = (wr & 1) ? W[2] : W[1];
  T[2] = (wr & 1) ? W[3] : W[2];
  T[3] = (wr & 1) ? W[0] : W[3];
  U[0] = (wr & 2) ? T[2] : T[0];
  U[1] = (wr & 2) ? T[3] : T[1];
  U[2] = (wr & 2) ? T[0] : T[2];
  U[3] = (wr & 2) ? T[1] : T[3];
  F[0] = (r & 1) ? funnel16(U[1], U[0]) : U[0];
  F[1] = (r & 1) ? funnel16(U[2], U[1]) : U[1];
  F[2] = (r & 1) ? funnel16(U[3], U[2]) : U[2];
  F[3] = (r & 1) ? funnel16(U[0], U[3]) : U[3];
  return __builtin_bit_cast(short8, F);
}

// ---------------------------------------------------------------------------
// cvt3: fp32 -> bf16 for three arrays (x, w_qkv, w_out), 8 elems/thread.
// ---------------------------------------------------------------------------
__global__ __launch_bounds__(256) void cvt3(
    const float* __restrict__ s0, bf16* __restrict__ d0, int n0,
    const float* __restrict__ s1, bf16* __restrict__ d1, int n1,
    const float* __restrict__ s2, bf16* __restrict__ d2, int n2) {
  int i = (blockIdx.x * 256 + threadIdx.x) * 8;
  if (i < n0) {
    *(short8*)&d0[i] = ld8bf(s0 + i);
  } else if ((i -= n0) < n1) {
    *(short8*)&d1[i] = ld8bf(s1 + i);
  } else if ((i -= n1) < n2) {
    *(short8*)&d2[i] = ld8bf(s2 + i);
  }
}

// ---------------------------------------------------------------------------
// FAST GEMM (m97 structure): all-bf16, global_load_lds width-16, 128x128 tile.
// ---------------------------------------------------------------------------
template <typename OT>
__global__ __launch_bounds__(256, 2) void gemm_lds_bias(
    const bf16* __restrict__ A, const bf16* __restrict__ B,
    const float* __restrict__ bias, OT* __restrict__ C, int M, int N, int K) {
  __shared__ bf16 As[128][64];
  __shared__ bf16 Bs[128][64];

  const int tid = threadIdx.x;
  const int w = tid >> 6, l = tid & 63;
  const int wr = w >> 1, wc = w & 1;
  const int m0 = blockIdx.y * 128, n0 = blockIdx.x * 128;

  f32x4 acc[4][4] = {};

  const int srow = l >> 3;
  const int scol = (l & 7) * 8;

  for (int kt = 0; kt < K; kt += 64) {
#pragma unroll
    for (int j = 0; j < 4; ++j) {
      int chunk = w * 4 + j;
      int row = chunk * 8 + srow;
      GLD16(A + (size_t)(m0 + row) * K + kt + scol, &As[0][0] + chunk * 512);
      GLD16(B + (size_t)(n0 + row) * K + kt + scol, &Bs[0][0] + chunk * 512);
    }
    __syncthreads();

#pragma unroll
    for (int kk = 0; kk < 2; ++kk) {
      short8 af[4], bfv[4];
#pragma unroll
      for (int i = 0; i < 4; ++i) {
        af[i]  = *(const short8*)&As[wr * 64 + i * 16 + (l & 15)]
                                   [kk * 32 + (l >> 4) * 8];
        bfv[i] = *(const short8*)&Bs[wc * 64 + i * 16 + (l & 15)]
                                   [kk * 32 + (l >> 4) * 8];
      }
#pragma unroll
      for (int i = 0; i < 4; ++i)
#pragma unroll
        for (int jn = 0; jn < 4; ++jn)
          acc[i][jn] = MFMA16(af[i], bfv[jn], acc[i][jn]);
    }
    __syncthreads();
  }

#pragma unroll
  for (int i = 0; i < 4; ++i) {
    int rbase = m0 + wr * 64 + i * 16 + (l >> 4) * 4;
#pragma unroll
    for (int jn = 0; jn < 4; ++jn) {
      int col = n0 + wc * 64 + jn * 16 + (l & 15);
      float bv = bias[col];
#pragma unroll
      for (int r = 0; r < 4; ++r)
        st1(&C[(size_t)(rbase + r) * N + col], acc[i][jn][r] + bv);
    }
  }
}

// ---------------------------------------------------------------------------
// FALLBACK GEMM (reg-staged, fp32/bf16 template) — used if ws too small.
// ---------------------------------------------------------------------------
template <typename AT, typename OT>
__global__ __launch_bounds__(256, 2) void gemm_bt_bias(
    const AT* __restrict__ A, const float* __restrict__ B,
    const float* __restrict__ bias, OT* __restrict__ C, int M, int N, int K) {
  __shared__ bf16 As[128][64];
  __shared__ bf16 Bs[128][64];

  const int tid = threadIdx.x;
  const int w = tid >> 6, l = tid & 63;
  const int wr = w >> 1, wc = w & 1;
  const int m0 = blockIdx.y * 128, n0 = blockIdx.x * 128;

  f32x4 acc[4][4] = {};

  const int srow = tid >> 3;
  const int scol = (tid & 7) * 8;

  for (int kt = 0; kt < K; kt += 64) {
    short8 aReg[4], bReg[4];
#pragma unroll
    for (int p = 0; p < 4; ++p) {
      int row = p * 32 + srow;
      aReg[p] = ld8bf(A + (size_t)(m0 + row) * K + kt + scol);
      bReg[p] = ld8bf(B + (size_t)(n0 + row) * K + kt + scol);
    }
    __syncthreads();
#pragma unroll
    for (int p = 0; p < 4; ++p) {
      int row = p * 32 + srow;
      *(short8*)&As[row][scol] = aReg[p];
      *(short8*)&Bs[row][scol] = bReg[p];
    }
    __syncthreads();

#pragma unroll
    for (int kk = 0; kk < 2; ++kk) {
      short8 af[4], bfv[4];
#pragma unroll
      for (int i = 0; i < 4; ++i) {
        af[i]  = *(const short8*)&As[wr * 64 + i * 16 + (l & 15)]
                                   [kk * 32 + (l >> 4) * 8];
        bfv[i] = *(const short8*)&Bs[wc * 64 + i * 16 + (l & 15)]
                                   [kk * 32 + (l >> 4) * 8];
      }
#pragma unroll
      for (int i = 0; i < 4; ++i)
#pragma unroll
        for (int jn = 0; jn < 4; ++jn)
          acc[i][jn] = MFMA16(af[i], bfv[jn], acc[i][jn]);
    }
  }

#pragma unroll
  for (int i = 0; i < 4; ++i) {
    int rbase = m0 + wr * 64 + i * 16 + (l >> 4) * 4;
#pragma unroll
    for (int jn = 0; jn < 4; ++jn) {
      int col = n0 + wc * 64 + jn * 16 + (l & 15);
      float bv = bias[col];
#pragma unroll
      for (int r = 0; r < 4; ++r)
        st1(&C[(size_t)(rbase + r) * N + col], acc[i][jn][r] + bv);
    }
  }
}

// ---------------------------------------------------------------------------
// Flash attention, swapped-operand 32x32 MFMA.
// R7-proven 2-barrier single-buffer pipeline + XCD swizzle + KVBLK=128
// (halves barrier count and per-tile serial-chain overhead vs KVBLK=64).
// ---------------------------------------------------------------------------
__global__ __launch_bounds__(256, 2) void attn_fwd(
    const bf16* __restrict__ qkv, bf16* __restrict__ attended) {
  const int S = 2048, D3 = 3072, D = 1024;
  // bijective XCD swizzle (512 = 8 x 64): each XCD owns 4 bh values entirely
  // -> K/V (~2 MB/XCD) stays L2-resident (R8: FETCH_SIZE 69.7 -> 12.5 MB).
  const int flat = blockIdx.y * 16 + blockIdx.x;
  const int n = (flat & 7) * 64 + (flat >> 3);
  const int qt = n & 15, bh = n >> 4;
  const int b = bh >> 4, h = bh & 15;
  const int tid = threadIdx.x, w = tid >> 6, l = tid & 63;
  const int lo5 = l & 31, hi = l >> 5;

  __shared__ bf16 Klds[128][72];  // 18.4 KB, K[kv][e], row stride 144B (16|144)
  __shared__ bf16 Vt[64][136];    // 17.4 KB, V^T[e][kv], row stride 272B

  const int q0w = qt * 128 + w * 32;

  short8 qf[4];
  {
    size_t qrow = (size_t)(b * S + q0w + lo5) * D3 + h * 64;
#pragma unroll
    for (int ks = 0; ks < 4; ++ks)
      qf[ks] = *(const short8*)&qkv[qrow + ks * 16 + hi * 8];
  }

  float m_raw = -1e30f, l_i = 0.f;
  f32x16 o0 = {}, o1 = {};

  const float Cs = 0.125f * 1.44269504088896340736f;  // hd^-0.5 * log2(e)

  const int srow = tid >> 2;   // 0..63 (also covers srow+64)
  const int scq = tid & 3;     // 16-col chunk
  const size_t gb0 = (size_t)(b * S + srow) * D3 + h * 64 + scq * 16;
  const size_t HSTEP = (size_t)64 * D3;   // 64 kv rows

  short8 k0, k1, k2, k3, v0, v1, v2, v3;
  // prologue: tile 0 (128 kv rows) -> regs
  {
    const bf16* g = qkv + gb0;
    k0 = *(const short8*)&g[1024];
    k1 = *(const short8*)&g[1024 + 8];
    v0 = *(const short8*)&g[2048];
    v1 = *(const short8*)&g[2048 + 8];
    const bf16* g2 = g + HSTEP;
    k2 = *(const short8*)&g2[1024];
    k3 = *(const short8*)&g2[1024 + 8];
    v2 = *(const short8*)&g2[2048];
    v3 = *(const short8*)&g2[2048 + 8];
  }

// pack one 32-kv block of P (f32x16 SV, bf16-exp'd in place) into po[G]
#define PACKP(G, SV)                                                           \
  {                                                                            \
    _Pragma("unroll") for (int tq = 0; tq < 4; ++tq) {                         \
      po[G][tq][0] = pk2((SV)[4 * tq], (SV)[4 * tq + 1]);                      \
      po[G][tq][1] = pk2((SV)[4 * tq + 2], (SV)[4 * tq + 3]);                  \
    }                                                                          \
  }

  for (int t = 0; t < 16; ++t) {
    __syncthreads();  // WAR: previous tile's LDS readers done
    // stage K (rows srow, srow+64)
    *(short8*)&Klds[srow][scq * 16] = k0;
    *(short8*)&Klds[srow][scq * 16 + 8] = k1;
    *(short8*)&Klds[64 + srow][scq * 16] = k2;
    *(short8*)&Klds[64 + srow][scq * 16 + 8] = k3;
    // stage V^T (rotation scatter, R7-measured conflict-free pattern)
#pragma unroll
    for (int g = 0; g < 2; ++g) {
      int sI = scq * 2 + g;
      short8 ua = rotl8(g ? v1 : v0, sI);
      short8 ub = rotl8(g ? v3 : v2, sI);
#pragma unroll
      for (int j = 0; j < 8; ++j) {
        int jj = (j + sI) & 7;
        *(short*)&Vt[sI * 8 + jj][srow] = (short)ua[j];
        *(short*)&Vt[sI * 8 + jj][64 + srow] = (short)ub[j];
      }
    }
    __syncthreads();  // writes visible

    // prefetch next tile's K (V prefetch deferred past QK to cap VGPR peak)
    if (t + 1 < 16) {
      const bf16* g = qkv + gb0 + (size_t)(t + 1) * 2 * HSTEP;
      k0 = *(const short8*)&g[1024];
      k1 = *(const short8*)&g[1024 + 8];
      k2 = *(const short8*)&g[HSTEP + 1024];
      k3 = *(const short8*)&g[HSTEP + 1024 + 8];
    }

    // S^T = K @ Q^T  (4 kv-row-blocks of 32)
    f32x16 s0 = {}, s1 = {}, s2 = {}, s3 = {};
    __builtin_amdgcn_s_setprio(1);
#pragma unroll
    for (int ks = 0; ks < 4; ++ks) {
      short8 km0 = *(const short8*)&Klds[lo5][ks * 16 + hi * 8];
      short8 km1 = *(const short8*)&Klds[32 + lo5][ks * 16 + hi * 8];
      short8 km2 = *(const short8*)&Klds[64 + lo5][ks * 16 + hi * 8];
      short8 km3 = *(const short8*)&Klds[96 + lo5][ks * 16 + hi * 8];
      s0 = MFMA32(km0, qf[ks], s0);
      s1 = MFMA32(km1, qf[ks], s1);
      s2 = MFMA32(km2, qf[ks], s2);
      s3 = MFMA32(km3, qf[ks], s3);
    }
    __builtin_amdgcn_s_setprio(0);

    // prefetch next tile's V
    if (t + 1 < 16) {
      const bf16* g = qkv + gb0 + (size_t)(t + 1) * 2 * HSTEP;
      v0 = *(const short8*)&g[2048];
      v1 = *(const short8*)&g[2048 + 8];
      v2 = *(const short8*)&g[HSTEP + 2048];
      v3 = *(const short8*)&g[HSTEP + 2048 + 8];
    }

    // per-lane online softmax over 128 kv (q = lo5), defer-max THR=8
    f32x16 tm;
#pragma unroll
    for (int r = 0; r < 16; ++r)
      tm[r] = fmaxf(fmaxf(s0[r], s1[r]), fmaxf(s2[r], s3[r]));
#pragma unroll
    for (int st = 8; st > 0; st >>= 1)
#pragma unroll
      for (int r = 0; r < st; ++r) tm[r] = fmaxf(tm[r], tm[r + st]);
    float mx = fmaxf(tm[0], __shfl_xor(tm[0], 32));

    bool deferred = __all((mx - m_raw) * Cs <= 8.0f);
    float mn, alpha;
    if (deferred) {
      mn = m_raw;
      alpha = 1.0f;
    } else {
      mn = fmaxf(m_raw, mx);
      alpha = __builtin_amdgcn_exp2f((m_raw - mn) * Cs);
      m_raw = mn;
    }
    float pc = mn * Cs;

#pragma unroll
    for (int r = 0; r < 16; ++r) {
      s0[r] = __builtin_amdgcn_exp2f(__builtin_fmaf(s0[r], Cs, -pc));
      s1[r] = __builtin_amdgcn_exp2f(__builtin_fmaf(s1[r], Cs, -pc));
      s2[r] = __builtin_amdgcn_exp2f(__builtin_fmaf(s2[r], Cs, -pc));
      s3[r] = __builtin_amdgcn_exp2f(__builtin_fmaf(s3[r], Cs, -pc));
    }
    f32x16 ts;
#pragma unroll
    for (int r = 0; r < 16; ++r)
      ts[r] = (s0[r] + s1[r]) + (s2[r] + s3[r]);
#pragma unroll
    for (int st = 8; st > 0; st >>= 1)
#pragma unroll
      for (int r = 0; r < st; ++r) ts[r] += ts[r + st];
    float sf = ts[0] + __shfl_xor(ts[0], 32);
    if (deferred) {
      l_i += sf;
    } else {
      l_i = l_i * alpha + sf;
      o0 *= alpha;
      o1 *= alpha;
    }

    // pack P quads (po[g][tq][hf]: kv = 32g + 8tq + 4hi + {0..3})
    unsigned po[4][4][2];
    PACKP(0, s0) PACKP(1, s1) PACKP(2, s2) PACKP(3, s3)
    // partner-lane exchange: 1 shfl per needed u32
    unsigned pr[4][2][2];
#pragma unroll
    for (int g = 0; g < 4; ++g)
#pragma unroll
      for (int p = 0; p < 2; ++p)
#pragma unroll
        for (int hf = 0; hf < 2; ++hf) {
          unsigned y = hi ? po[g][2 * p][hf] : po[g][2 * p + 1][hf];
          pr[g][p][hf] = (unsigned)__shfl_xor((int)y, 32);
        }

    // O^T += V^T @ P^T  (8 k-slots of 16)
    __builtin_amdgcn_s_setprio(1);
#pragma unroll
    for (int ks2 = 0; ks2 < 8; ++ks2) {
      const int g = ks2 >> 1, p = ks2 & 1;
      u32x4 fw;
      fw[0] = hi ? pr[g][p][0] : po[g][2 * p][0];
      fw[1] = hi ? pr[g][p][1] : po[g][2 * p][1];
      fw[2] = hi ? po[g][2 * p + 1][0] : pr[g][p][0];
      fw[3] = hi ? po[g][2 * p + 1][1] : pr[g][p][1];
      short8 pf = __builtin_bit_cast(short8, fw);
      short8 va0 = *(const short8*)&Vt[lo5][ks2 * 16 + hi * 8];
      short8 va1 = *(const short8*)&Vt[32 + lo5][ks2 * 16 + hi * 8];
      o0 = MFMA32(va0, pf, o0);
      o1 = MFMA32(va1, pf, o1);
    }
    __builtin_amdgcn_s_setprio(0);
  }

  float inv = 1.0f / l_i;
  size_t orow = (size_t)(b * S + q0w + lo5) * D + h * 64;
#pragma unroll
  for (int t = 0; t < 4; ++t) {
    u32x2 w0, w1;
    w0[0] = pk2(o0[4 * t] * inv, o0[4 * t + 1] * inv);
    w0[1] = pk2(o0[4 * t + 2] * inv, o0[4 * t + 3] * inv);
    w1[0] = pk2(o1[4 * t] * inv, o1[4 * t + 1] * inv);
    w1[1] = pk2(o1[4 * t + 2] * inv, o1[4 * t + 3] * inv);
    *(u32x2*)&attended[orow + 8 * t + 4 * hi] = w0;
    *(u32x2*)&attended[orow + 32 + 8 * t + 4 * hi] = w1;
  }
}

// ---------------------------------------------------------------------------
extern "C" void kernel_launch(void* const* d_in, const int* in_sizes, int n_in,
                              void* d_out, int out_size, void* d_ws,
                              size_t ws_size, hipStream_t stream) {
  const float* x     = (const float*)d_in[0];   // [2,2048,1024] fp32
  const float* w_qkv = (const float*)d_in[1];   // [3072,1024]   fp32
  const float* b_qkv = (const float*)d_in[2];   // [3072]        fp32
  const float* w_out = (const float*)d_in[3];   // [1024,1024]   fp32
  const float* b_out = (const float*)d_in[4];   // [1024]        fp32
  float* out = (float*)d_out;                   // [2,2048,1024] fp32

  const int BS = 4096;   // B*S
  const int D = 1024, D3 = 3072;
  const int NX = BS * D, NWQ = D3 * D, NWO = D * D;

  bf16* qkv = (bf16*)d_ws;                       // [4096][3072] 25.2 MB
  bf16* att = qkv + (size_t)BS * D3;             // [4096][1024]  8.4 MB

  const size_t NEED = ((size_t)BS * D3 + (size_t)BS * D + (size_t)D3 * D +
                       (size_t)D * D) * sizeof(bf16);

  if (ws_size >= NEED) {
    bf16* xb  = att;                             // overlaid with att
    bf16* wqb = xb + (size_t)NX;
    bf16* wob = wqb + (size_t)NWQ;

    int ncvt = (NX + NWQ + NWO) / 8;
    cvt3<<<(ncvt + 255) / 256, 256, 0, stream>>>(x, xb, NX, w_qkv, wqb, NWQ,
                                                 w_out, wob, NWO);
    gemm_lds_bias<bf16><<<dim3(D3 / 128, BS / 128), 256, 0, stream>>>(
        xb, wqb, b_qkv, qkv, BS, D3, D);
    attn_fwd<<<dim3(16, 32), 256, 0, stream>>>(qkv, att);  // clobbers xb/wqb
    gemm_lds_bias<float><<<dim3(D / 128, BS / 128), 256, 0, stream>>>(
        att, wob, b_out, out, BS, D, D);
  } else {
    gemm_bt_bias<float, bf16><<<dim3(D3 / 128, BS / 128), 256, 0, stream>>>(
        x, w_qkv, b_qkv, qkv, BS, D3, D);
    attn_fwd<<<dim3(16, 32), 256, 0, stream>>>(qkv, att);
    gemm_bt_bias<bf16, float><<<dim3(D / 128, BS / 128), 256, 0, stream>>>(
        att, w_out, b_out, out, BS, D, D);
  }
}

// Round 10
// 122.652 us; speedup vs baseline: 1.1630x; 1.0377x over previous
//
#include <hip/hip_runtime.h>
#include <hip/hip_bf16.h>

typedef __hip_bfloat16 bf16;
typedef __attribute__((ext_vector_type(8))) short short8;
typedef __attribute__((ext_vector_type(8))) __bf16 bf16x8;
typedef __attribute__((ext_vector_type(4))) float f32x4;
typedef __attribute__((ext_vector_type(16))) float f32x16;
typedef __attribute__((ext_vector_type(4))) unsigned int u32x4;
typedef __attribute__((ext_vector_type(2))) unsigned int u32x2;

// 16x16x32: C/D col = lane&15, row = (lane>>4)*4 + reg  [m89/m91]
#define MFMA16(a, b, c)                                                        \
  __builtin_amdgcn_mfma_f32_16x16x32_bf16(__builtin_bit_cast(bf16x8, (a)),     \
                                          __builtin_bit_cast(bf16x8, (b)),     \
                                          (c), 0, 0, 0)
// 32x32x16: C/D col = lane&31, row = (reg&3)+8*(reg>>2)+4*(lane>>5) [m74/m101]
#define MFMA32(a, b, c)                                                        \
  __builtin_amdgcn_mfma_f32_32x32x16_bf16(__builtin_bit_cast(bf16x8, (a)),     \
                                          __builtin_bit_cast(bf16x8, (b)),     \
                                          (c), 0, 0, 0)

// async global->LDS, 16B/lane; LDS dest = wave-uniform base + lane*16 [m97]
#define GLD16(gsrc, ldst)                                                      \
  __builtin_amdgcn_global_load_lds(                                            \
      (const __attribute__((address_space(1))) void*)(gsrc),                   \
      (__attribute__((address_space(3))) void*)(ldst), 16, 0, 0)

__device__ inline short f2bfs(float f) {
  return __builtin_bit_cast(short, __float2bfloat16(f));
}
__device__ inline unsigned pk2(float lo, float hi) {
  unsigned a = (unsigned short)__builtin_bit_cast(short, __float2bfloat16(lo));
  unsigned b = (unsigned short)__builtin_bit_cast(short, __float2bfloat16(hi));
  return a | (b << 16);
}

template <typename T> __device__ inline short8 ld8bf(const T* p);
template <> __device__ inline short8 ld8bf<bf16>(const bf16* p) {
  return *(const short8*)p;
}
template <> __device__ inline short8 ld8bf<float>(const float* p) {
  f32x4 a = *(const f32x4*)p;
  f32x4 b = *(const f32x4*)(p + 4);
  short8 r;
  r[0] = f2bfs(a[0]); r[1] = f2bfs(a[1]); r[2] = f2bfs(a[2]); r[3] = f2bfs(a[3]);
  r[4] = f2bfs(b[0]); r[5] = f2bfs(b[1]); r[6] = f2bfs(b[2]); r[7] = f2bfs(b[3]);
  return r;
}

template <typename OT> __device__ inline void st1(OT* p, float v);
template <> __device__ inline void st1<bf16>(bf16* p, float v) {
  *p = __float2bfloat16(v);
}
template <> __device__ inline void st1<float>(float* p, float v) { *p = v; }

__device__ inline unsigned int funnel16(unsigned int hi, unsigned int lo) {
  return (unsigned int)(((((unsigned long long)hi) << 32) | lo) >> 16);
}
// u[j] = v[(j + r) & 7] — rotate 8 shorts left by r, all-static indexing.
__device__ inline short8 rotl8(short8 v, int r) {
  u32x4 W = __builtin_bit_cast(u32x4, v);
  u32x4 T, U, F;
  int wr = r >> 1;
  T[0] = (wr & 1) ? W[1] : W[0];
  T[1] = (wr & 1) ? W[2] : W[1];
  T[2] = (wr & 1) ? W[3] : W[2];
  T[3] = (wr & 1) ? W[0] : W[3];
  U[0] = (wr & 2) ? T[2] : T[0];
  U[1] = (wr & 2) ? T[3] : T[1];
  U[2] = (wr & 2) ? T[0] : T[2];
  U[3] = (wr & 2) ? T[1] : T[3];
  F[0] = (r & 1) ? funnel16(U[1], U[0]) : U[0];
  F[1] = (r & 1) ? funnel16(U[2], U[1]) : U[1];
  F[2] = (r & 1) ? funnel16(U[3], U[2]) : U[2];
  F[3] = (r & 1) ? funnel16(U[0], U[3]) : U[3];
  return __builtin_bit_cast(short8, F);
}

// ---------------------------------------------------------------------------
// cvt3: fp32 -> bf16 for three arrays (x, w_qkv, w_out), 8 elems/thread.
// ---------------------------------------------------------------------------
__global__ __launch_bounds__(256) void cvt3(
    const float* __restrict__ s0, bf16* __restrict__ d0, int n0,
    const float* __restrict__ s1, bf16* __restrict__ d1, int n1,
    const float* __restrict__ s2, bf16* __restrict__ d2, int n2) {
  int i = (blockIdx.x * 256 + threadIdx.x) * 8;
  if (i < n0) {
    *(short8*)&d0[i] = ld8bf(s0 + i);
  } else if ((i -= n0) < n1) {
    *(short8*)&d1[i] = ld8bf(s1 + i);
  } else if ((i -= n1) < n2) {
    *(short8*)&d2[i] = ld8bf(s2 + i);
  }
}

// ---------------------------------------------------------------------------
// FAST GEMM (m97 structure): all-bf16, global_load_lds width-16.
// Tile 128 x BN (BN = 128 or 64), BK=64, 256 thr = 2x2 waves.
// BN=64 variant doubles grid for occupancy-starved shapes (out-proj).
// ---------------------------------------------------------------------------
template <int BN, typename OT>
__global__ __launch_bounds__(256, 2) void gemm_lds_bias(
    const bf16* __restrict__ A, const bf16* __restrict__ B,
    const float* __restrict__ bias, OT* __restrict__ C, int M, int N, int K) {
  __shared__ bf16 As[128][64];
  __shared__ bf16 Bs[BN][64];

  const int tid = threadIdx.x;
  const int w = tid >> 6, l = tid & 63;
  const int wr = w >> 1, wc = w & 1;
  const int m0 = blockIdx.y * 128, n0 = blockIdx.x * BN;
  const int JN = BN / 64;           // wave-col fragment count (2 or 1 per 32)
  const int WCOL = BN / 2;          // wave col extent

  f32x4 acc[4][2 * JN] = {};

  const int srow = l >> 3;
  const int scol = (l & 7) * 8;

  for (int kt = 0; kt < K; kt += 64) {
#pragma unroll
    for (int j = 0; j < 4; ++j) {
      int chunk = w * 4 + j;
      int row = chunk * 8 + srow;
      GLD16(A + (size_t)(m0 + row) * K + kt + scol, &As[0][0] + chunk * 512);
    }
#pragma unroll
    for (int j = 0; j < BN / 32; ++j) {
      int chunk = w * (BN / 32) + j;
      int row = chunk * 8 + srow;
      GLD16(B + (size_t)(n0 + row) * K + kt + scol, &Bs[0][0] + chunk * 512);
    }
    __syncthreads();

#pragma unroll
    for (int kk = 0; kk < 2; ++kk) {
      short8 af[4], bfv[2 * JN];
#pragma unroll
      for (int i = 0; i < 4; ++i)
        af[i] = *(const short8*)&As[wr * 64 + i * 16 + (l & 15)]
                                  [kk * 32 + (l >> 4) * 8];
#pragma unroll
      for (int jn = 0; jn < 2 * JN; ++jn)
        bfv[jn] = *(const short8*)&Bs[wc * WCOL + jn * 16 + (l & 15)]
                                    [kk * 32 + (l >> 4) * 8];
#pragma unroll
      for (int i = 0; i < 4; ++i)
#pragma unroll
        for (int jn = 0; jn < 2 * JN; ++jn)
          acc[i][jn] = MFMA16(af[i], bfv[jn], acc[i][jn]);
    }
    __syncthreads();
  }

#pragma unroll
  for (int i = 0; i < 4; ++i) {
    int rbase = m0 + wr * 64 + i * 16 + (l >> 4) * 4;
#pragma unroll
    for (int jn = 0; jn < 2 * JN; ++jn) {
      int col = n0 + wc * WCOL + jn * 16 + (l & 15);
      float bv = bias[col];
#pragma unroll
      for (int r = 0; r < 4; ++r)
        st1(&C[(size_t)(rbase + r) * N + col], acc[i][jn][r] + bv);
    }
  }
}

// ---------------------------------------------------------------------------
// FALLBACK GEMM (reg-staged, fp32/bf16 template) — used if ws too small.
// ---------------------------------------------------------------------------
template <typename AT, typename OT>
__global__ __launch_bounds__(256, 2) void gemm_bt_bias(
    const AT* __restrict__ A, const float* __restrict__ B,
    const float* __restrict__ bias, OT* __restrict__ C, int M, int N, int K) {
  __shared__ bf16 As[128][64];
  __shared__ bf16 Bs[128][64];

  const int tid = threadIdx.x;
  const int w = tid >> 6, l = tid & 63;
  const int wr = w >> 1, wc = w & 1;
  const int m0 = blockIdx.y * 128, n0 = blockIdx.x * 128;

  f32x4 acc[4][4] = {};

  const int srow = tid >> 3;
  const int scol = (tid & 7) * 8;

  for (int kt = 0; kt < K; kt += 64) {
    short8 aReg[4], bReg[4];
#pragma unroll
    for (int p = 0; p < 4; ++p) {
      int row = p * 32 + srow;
      aReg[p] = ld8bf(A + (size_t)(m0 + row) * K + kt + scol);
      bReg[p] = ld8bf(B + (size_t)(n0 + row) * K + kt + scol);
    }
    __syncthreads();
#pragma unroll
    for (int p = 0; p < 4; ++p) {
      int row = p * 32 + srow;
      *(short8*)&As[row][scol] = aReg[p];
      *(short8*)&Bs[row][scol] = bReg[p];
    }
    __syncthreads();

#pragma unroll
    for (int kk = 0; kk < 2; ++kk) {
      short8 af[4], bfv[4];
#pragma unroll
      for (int i = 0; i < 4; ++i) {
        af[i]  = *(const short8*)&As[wr * 64 + i * 16 + (l & 15)]
                                   [kk * 32 + (l >> 4) * 8];
        bfv[i] = *(const short8*)&Bs[wc * 64 + i * 16 + (l & 15)]
                                   [kk * 32 + (l >> 4) * 8];
      }
#pragma unroll
      for (int i = 0; i < 4; ++i)
#pragma unroll
        for (int jn = 0; jn < 4; ++jn)
          acc[i][jn] = MFMA16(af[i], bfv[jn], acc[i][jn]);
    }
  }

#pragma unroll
  for (int i = 0; i < 4; ++i) {
    int rbase = m0 + wr * 64 + i * 16 + (l >> 4) * 4;
#pragma unroll
    for (int jn = 0; jn < 4; ++jn) {
      int col = n0 + wc * 64 + jn * 16 + (l & 15);
      float bv = bias[col];
#pragma unroll
      for (int r = 0; r < 4; ++r)
        st1(&C[(size_t)(rbase + r) * N + col], acc[i][jn][r] + bv);
    }
  }
}

// ---------------------------------------------------------------------------
// Flash attention, swapped-operand 32x32 MFMA, KVBLK=128 (R9 structure)
// + permlane32_swap P-exchange (replaces 16 shfl + 48 selects/tile)
// + max3-fused max tree.
// ---------------------------------------------------------------------------
__global__ __launch_bounds__(256, 2) void attn_fwd(
    const bf16* __restrict__ qkv, bf16* __restrict__ attended) {
  const int S = 2048, D3 = 3072, D = 1024;
  // bijective XCD swizzle (512 = 8 x 64): each XCD owns 4 bh values entirely.
  const int flat = blockIdx.y * 16 + blockIdx.x;
  const int n = (flat & 7) * 64 + (flat >> 3);
  const int qt = n & 15, bh = n >> 4;
  const int b = bh >> 4, h = bh & 15;
  const int tid = threadIdx.x, w = tid >> 6, l = tid & 63;
  const int lo5 = l & 31, hi = l >> 5;

  __shared__ bf16 Klds[128][72];  // K[kv][e], row stride 144B
  __shared__ bf16 Vt[64][136];    // V^T[e][kv], row stride 272B

  const int q0w = qt * 128 + w * 32;

  short8 qf[4];
  {
    size_t qrow = (size_t)(b * S + q0w + lo5) * D3 + h * 64;
#pragma unroll
    for (int ks = 0; ks < 4; ++ks)
      qf[ks] = *(const short8*)&qkv[qrow + ks * 16 + hi * 8];
  }

  float m_raw = -1e30f, l_i = 0.f;
  f32x16 o0 = {}, o1 = {};

  const float Cs = 0.125f * 1.44269504088896340736f;  // hd^-0.5 * log2(e)

  const int srow = tid >> 2;
  const int scq = tid & 3;
  const size_t gb0 = (size_t)(b * S + srow) * D3 + h * 64 + scq * 16;
  const size_t HSTEP = (size_t)64 * D3;

  short8 k0, k1, k2, k3, v0, v1, v2, v3;
  {
    const bf16* g = qkv + gb0;
    k0 = *(const short8*)&g[1024];
    k1 = *(const short8*)&g[1024 + 8];
    v0 = *(const short8*)&g[2048];
    v1 = *(const short8*)&g[2048 + 8];
    const bf16* g2 = g + HSTEP;
    k2 = *(const short8*)&g2[1024];
    k3 = *(const short8*)&g2[1024 + 8];
    v2 = *(const short8*)&g2[2048];
    v3 = *(const short8*)&g2[2048 + 8];
  }

#define PACKP(G, SV)                                                           \
  {                                                                            \
    _Pragma("unroll") for (int tq = 0; tq < 4; ++tq) {                         \
      po[G][tq][0] = pk2((SV)[4 * tq], (SV)[4 * tq + 1]);                      \
      po[G][tq][1] = pk2((SV)[4 * tq + 2], (SV)[4 * tq + 3]);                  \
    }                                                                          \
  }

  for (int t = 0; t < 16; ++t) {
    __syncthreads();  // WAR
    *(short8*)&Klds[srow][scq * 16] = k0;
    *(short8*)&Klds[srow][scq * 16 + 8] = k1;
    *(short8*)&Klds[64 + srow][scq * 16] = k2;
    *(short8*)&Klds[64 + srow][scq * 16 + 8] = k3;
#pragma unroll
    for (int g = 0; g < 2; ++g) {
      int sI = scq * 2 + g;
      short8 ua = rotl8(g ? v1 : v0, sI);
      short8 ub = rotl8(g ? v3 : v2, sI);
#pragma unroll
      for (int j = 0; j < 8; ++j) {
        int jj = (j + sI) & 7;
        *(short*)&Vt[sI * 8 + jj][srow] = (short)ua[j];
        *(short*)&Vt[sI * 8 + jj][64 + srow] = (short)ub[j];
      }
    }
    __syncthreads();

    if (t + 1 < 16) {  // prefetch next K
      const bf16* g = qkv + gb0 + (size_t)(t + 1) * 2 * HSTEP;
      k0 = *(const short8*)&g[1024];
      k1 = *(const short8*)&g[1024 + 8];
      k2 = *(const short8*)&g[HSTEP + 1024];
      k3 = *(const short8*)&g[HSTEP + 1024 + 8];
    }

    // S^T = K @ Q^T
    f32x16 s0 = {}, s1 = {}, s2 = {}, s3 = {};
    __builtin_amdgcn_s_setprio(1);
#pragma unroll
    for (int ks = 0; ks < 4; ++ks) {
      short8 km0 = *(const short8*)&Klds[lo5][ks * 16 + hi * 8];
      short8 km1 = *(const short8*)&Klds[32 + lo5][ks * 16 + hi * 8];
      short8 km2 = *(const short8*)&Klds[64 + lo5][ks * 16 + hi * 8];
      short8 km3 = *(const short8*)&Klds[96 + lo5][ks * 16 + hi * 8];
      s0 = MFMA32(km0, qf[ks], s0);
      s1 = MFMA32(km1, qf[ks], s1);
      s2 = MFMA32(km2, qf[ks], s2);
      s3 = MFMA32(km3, qf[ks], s3);
    }
    __builtin_amdgcn_s_setprio(0);

    if (t + 1 < 16) {  // prefetch next V
      const bf16* g = qkv + gb0 + (size_t)(t + 1) * 2 * HSTEP;
      v0 = *(const short8*)&g[2048];
      v1 = *(const short8*)&g[2048 + 8];
      v2 = *(const short8*)&g[HSTEP + 2048];
      v3 = *(const short8*)&g[HSTEP + 2048 + 8];
    }

    // max over 128 kv (max3-fused trees)
    f32x16 tm;
#pragma unroll
    for (int r = 0; r < 16; ++r)
      tm[r] = fmaxf(fmaxf(fmaxf(s0[r], s1[r]), s2[r]), s3[r]);
    float a0 = fmaxf(fmaxf(tm[0], tm[1]), tm[2]);
    float a1 = fmaxf(fmaxf(tm[3], tm[4]), tm[5]);
    float a2 = fmaxf(fmaxf(tm[6], tm[7]), tm[8]);
    float a3 = fmaxf(fmaxf(tm[9], tm[10]), tm[11]);
    float a4 = fmaxf(fmaxf(tm[12], tm[13]), tm[14]);
    float b0v = fmaxf(fmaxf(a0, a1), a2);
    float b1v = fmaxf(fmaxf(a3, a4), tm[15]);
    float mx = fmaxf(b0v, b1v);
    mx = fmaxf(mx, __shfl_xor(mx, 32));

    bool deferred = __all((mx - m_raw) * Cs <= 8.0f);
    float mn, alpha;
    if (deferred) {
      mn = m_raw;
      alpha = 1.0f;
    } else {
      mn = fmaxf(m_raw, mx);
      alpha = __builtin_amdgcn_exp2f((m_raw - mn) * Cs);
      m_raw = mn;
    }
    float pc = mn * Cs;

#pragma unroll
    for (int r = 0; r < 16; ++r) {
      s0[r] = __builtin_amdgcn_exp2f(__builtin_fmaf(s0[r], Cs, -pc));
      s1[r] = __builtin_amdgcn_exp2f(__builtin_fmaf(s1[r], Cs, -pc));
      s2[r] = __builtin_amdgcn_exp2f(__builtin_fmaf(s2[r], Cs, -pc));
      s3[r] = __builtin_amdgcn_exp2f(__builtin_fmaf(s3[r], Cs, -pc));
    }
    f32x16 ts;
#pragma unroll
    for (int r = 0; r < 16; ++r)
      ts[r] = (s0[r] + s1[r]) + (s2[r] + s3[r]);
#pragma unroll
    for (int st = 8; st > 0; st >>= 1)
#pragma unroll
      for (int r = 0; r < st; ++r) ts[r] += ts[r + st];
    float sf = ts[0] + __shfl_xor(ts[0], 32);
    if (deferred) {
      l_i += sf;
    } else {
      l_i = l_i * alpha + sf;
      o0 *= alpha;
      o1 *= alpha;
    }

    // pack P quads (po[g][tq][hf]: kv = 32g + 8tq + 4hi + {0..3})
    unsigned po[4][4][2];
    PACKP(0, s0) PACKP(1, s1) PACKP(2, s2) PACKP(3, s3)

    // O^T += V^T @ P^T; B-fragment via permlane32_swap:
    //   swap(even,odd) -> x = {own-even | partner-odd}, y = {partner-even |
    //   own-odd}; fw = {x0, x1(hf=1), y0, y1} is uniform across lanes.
    __builtin_amdgcn_s_setprio(1);
#pragma unroll
    for (int ks2 = 0; ks2 < 8; ++ks2) {
      const int g = ks2 >> 1, p = ks2 & 1;
      u32x2 ra = __builtin_amdgcn_permlane32_swap(po[g][2 * p][0],
                                                  po[g][2 * p + 1][0],
                                                  false, false);
      u32x2 rb = __builtin_amdgcn_permlane32_swap(po[g][2 * p][1],
                                                  po[g][2 * p + 1][1],
                                                  false, false);
      u32x4 fw;
      fw[0] = ra[0];
      fw[1] = rb[0];
      fw[2] = ra[1];
      fw[3] = rb[1];
      short8 pf = __builtin_bit_cast(short8, fw);
      short8 va0 = *(const short8*)&Vt[lo5][ks2 * 16 + hi * 8];
      short8 va1 = *(const short8*)&Vt[32 + lo5][ks2 * 16 + hi * 8];
      o0 = MFMA32(va0, pf, o0);
      o1 = MFMA32(va1, pf, o1);
    }
    __builtin_amdgcn_s_setprio(0);
  }

  float inv = 1.0f / l_i;
  size_t orow = (size_t)(b * S + q0w + lo5) * D + h * 64;
#pragma unroll
  for (int t = 0; t < 4; ++t) {
    u32x2 w0, w1;
    w0[0] = pk2(o0[4 * t] * inv, o0[4 * t + 1] * inv);
    w0[1] = pk2(o0[4 * t + 2] * inv, o0[4 * t + 3] * inv);
    w1[0] = pk2(o1[4 * t] * inv, o1[4 * t + 1] * inv);
    w1[1] = pk2(o1[4 * t + 2] * inv, o1[4 * t + 3] * inv);
    *(u32x2*)&attended[orow + 8 * t + 4 * hi] = w0;
    *(u32x2*)&attended[orow + 32 + 8 * t + 4 * hi] = w1;
  }
}

// ---------------------------------------------------------------------------
extern "C" void kernel_launch(void* const* d_in, const int* in_sizes, int n_in,
                              void* d_out, int out_size, void* d_ws,
                              size_t ws_size, hipStream_t stream) {
  const float* x     = (const float*)d_in[0];   // [2,2048,1024] fp32
  const float* w_qkv = (const float*)d_in[1];   // [3072,1024]   fp32
  const float* b_qkv = (const float*)d_in[2];   // [3072]        fp32
  const float* w_out = (const float*)d_in[3];   // [1024,1024]   fp32
  const float* b_out = (const float*)d_in[4];   // [1024]        fp32
  float* out = (float*)d_out;                   // [2,2048,1024] fp32

  const int BS = 4096;   // B*S
  const int D = 1024, D3 = 3072;
  const int NX = BS * D, NWQ = D3 * D, NWO = D * D;

  bf16* qkv = (bf16*)d_ws;                       // [4096][3072] 25.2 MB
  bf16* att = qkv + (size_t)BS * D3;             // [4096][1024]  8.4 MB

  const size_t NEED = ((size_t)BS * D3 + (size_t)BS * D + (size_t)D3 * D +
                       (size_t)D * D) * sizeof(bf16);

  if (ws_size >= NEED) {
    bf16* xb  = att;                             // overlaid with att
    bf16* wqb = xb + (size_t)NX;
    bf16* wob = wqb + (size_t)NWQ;

    int ncvt = (NX + NWQ + NWO) / 8;
    cvt3<<<(ncvt + 255) / 256, 256, 0, stream>>>(x, xb, NX, w_qkv, wqb, NWQ,
                                                 w_out, wob, NWO);
    gemm_lds_bias<128, bf16><<<dim3(D3 / 128, BS / 128), 256, 0, stream>>>(
        xb, wqb, b_qkv, qkv, BS, D3, D);
    attn_fwd<<<dim3(16, 32), 256, 0, stream>>>(qkv, att);  // clobbers xb/wqb
    gemm_lds_bias<64, float><<<dim3(D / 64, BS / 128), 256, 0, stream>>>(
        att, wob, b_out, out, BS, D, D);
  } else {
    gemm_bt_bias<float, bf16><<<dim3(D3 / 128, BS / 128), 256, 0, stream>>>(
        x, w_qkv, b_qkv, qkv, BS, D3, D);
    attn_fwd<<<dim3(16, 32), 256, 0, stream>>>(qkv, att);
    gemm_bt_bias<bf16, float><<<dim3(D / 128, BS / 128), 256, 0, stream>>>(
        att, w_out, b_out, out, BS, D, D);
  }
}

// Round 11
// 119.746 us; speedup vs baseline: 1.1912x; 1.0243x over previous
//
#include <hip/hip_runtime.h>
#include <hip/hip_bf16.h>

typedef __hip_bfloat16 bf16;
typedef __attribute__((ext_vector_type(8))) short short8;
typedef __attribute__((ext_vector_type(8))) __bf16 bf16x8;
typedef __attribute__((ext_vector_type(4))) float f32x4;
typedef __attribute__((ext_vector_type(16))) float f32x16;
typedef __attribute__((ext_vector_type(4))) unsigned int u32x4;
typedef __attribute__((ext_vector_type(2))) unsigned int u32x2;

// 16x16x32: C/D col = lane&15, row = (lane>>4)*4 + reg  [m89/m91]
#define MFMA16(a, b, c)                                                        \
  __builtin_amdgcn_mfma_f32_16x16x32_bf16(__builtin_bit_cast(bf16x8, (a)),     \
                                          __builtin_bit_cast(bf16x8, (b)),     \
                                          (c), 0, 0, 0)
// 32x32x16: C/D col = lane&31, row = (reg&3)+8*(reg>>2)+4*(lane>>5) [m74/m101]
#define MFMA32(a, b, c)                                                        \
  __builtin_amdgcn_mfma_f32_32x32x16_bf16(__builtin_bit_cast(bf16x8, (a)),     \
                                          __builtin_bit_cast(bf16x8, (b)),     \
                                          (c), 0, 0, 0)

// async global->LDS, 16B/lane; LDS dest = wave-uniform base + lane*16 [m97]
#define GLD16(gsrc, ldst)                                                      \
  __builtin_amdgcn_global_load_lds(                                            \
      (const __attribute__((address_space(1))) void*)(gsrc),                   \
      (__attribute__((address_space(3))) void*)(ldst), 16, 0, 0)

// ONE instruction: packs 2 f32 -> 2 bf16 in a u32 (RNE). No builtin on
// gfx950 (m240); __float2bfloat16 pairs cost ~11 VALU ops instead.
__device__ inline unsigned pk2(float lo, float hi) {
  unsigned r;
  asm("v_cvt_pk_bf16_f32 %0, %1, %2" : "=v"(r) : "v"(lo), "v"(hi));
  return r;
}
__device__ inline short f2bfs(float f) {
  return __builtin_bit_cast(short, __float2bfloat16(f));
}

template <typename T> __device__ inline short8 ld8bf(const T* p);
template <> __device__ inline short8 ld8bf<bf16>(const bf16* p) {
  return *(const short8*)p;
}
template <> __device__ inline short8 ld8bf<float>(const float* p) {
  f32x4 a = *(const f32x4*)p;
  f32x4 b = *(const f32x4*)(p + 4);
  u32x4 r;
  r[0] = pk2(a[0], a[1]);
  r[1] = pk2(a[2], a[3]);
  r[2] = pk2(b[0], b[1]);
  r[3] = pk2(b[2], b[3]);
  return __builtin_bit_cast(short8, r);
}

template <typename OT> __device__ inline void st1(OT* p, float v);
template <> __device__ inline void st1<bf16>(bf16* p, float v) {
  *p = __float2bfloat16(v);
}
template <> __device__ inline void st1<float>(float* p, float v) { *p = v; }

__device__ inline unsigned int funnel16(unsigned int hi, unsigned int lo) {
  return (unsigned int)(((((unsigned long long)hi) << 32) | lo) >> 16);
}
// u[j] = v[(j + r) & 7] — rotate 8 shorts left by r, all-static indexing.
__device__ inline short8 rotl8(short8 v, int r) {
  u32x4 W = __builtin_bit_cast(u32x4, v);
  u32x4 T, U, F;
  int wr = r >> 1;
  T[0] = (wr & 1) ? W[1] : W[0];
  T[1] = (wr & 1) ? W[2] : W[1];
  T[2] = (wr & 1) ? W[3] : W[2];
  T[3] = (wr & 1) ? W[0] : W[3];
  U[0] = (wr & 2) ? T[2] : T[0];
  U[1] = (wr & 2) ? T[3] : T[1];
  U[2] = (wr & 2) ? T[0] : T[2];
  U[3] = (wr & 2) ? T[1] : T[3];
  F[0] = (r & 1) ? funnel16(U[1], U[0]) : U[0];
  F[1] = (r & 1) ? funnel16(U[2], U[1]) : U[1];
  F[2] = (r & 1) ? funnel16(U[3], U[2]) : U[2];
  F[3] = (r & 1) ? funnel16(U[0], U[3]) : U[3];
  return __builtin_bit_cast(short8, F);
}

// ---------------------------------------------------------------------------
// cvt3: fp32 -> bf16 for three arrays (x, w_qkv, w_out), 8 elems/thread.
// ---------------------------------------------------------------------------
__global__ __launch_bounds__(256) void cvt3(
    const float* __restrict__ s0, bf16* __restrict__ d0, int n0,
    const float* __restrict__ s1, bf16* __restrict__ d1, int n1,
    const float* __restrict__ s2, bf16* __restrict__ d2, int n2) {
  int i = (blockIdx.x * 256 + threadIdx.x) * 8;
  if (i < n0) {
    *(short8*)&d0[i] = ld8bf(s0 + i);
  } else if ((i -= n0) < n1) {
    *(short8*)&d1[i] = ld8bf(s1 + i);
  } else if ((i -= n1) < n2) {
    *(short8*)&d2[i] = ld8bf(s2 + i);
  }
}

// ---------------------------------------------------------------------------
// FAST GEMM (m97 structure): all-bf16, global_load_lds width-16.
// Tile 128 x BN (BN = 128 or 64), BK=64, 256 thr = 2x2 waves.
// ---------------------------------------------------------------------------
template <int BN, typename OT>
__global__ __launch_bounds__(256, 2) void gemm_lds_bias(
    const bf16* __restrict__ A, const bf16* __restrict__ B,
    const float* __restrict__ bias, OT* __restrict__ C, int M, int N, int K) {
  __shared__ bf16 As[128][64];
  __shared__ bf16 Bs[BN][64];

  const int tid = threadIdx.x;
  const int w = tid >> 6, l = tid & 63;
  const int wr = w >> 1, wc = w & 1;
  const int m0 = blockIdx.y * 128, n0 = blockIdx.x * BN;
  const int JN = BN / 64;
  const int WCOL = BN / 2;

  f32x4 acc[4][2 * JN] = {};

  const int srow = l >> 3;
  const int scol = (l & 7) * 8;

  for (int kt = 0; kt < K; kt += 64) {
#pragma unroll
    for (int j = 0; j < 4; ++j) {
      int chunk = w * 4 + j;
      int row = chunk * 8 + srow;
      GLD16(A + (size_t)(m0 + row) * K + kt + scol, &As[0][0] + chunk * 512);
    }
#pragma unroll
    for (int j = 0; j < BN / 32; ++j) {
      int chunk = w * (BN / 32) + j;
      int row = chunk * 8 + srow;
      GLD16(B + (size_t)(n0 + row) * K + kt + scol, &Bs[0][0] + chunk * 512);
    }
    __syncthreads();

#pragma unroll
    for (int kk = 0; kk < 2; ++kk) {
      short8 af[4], bfv[2 * JN];
#pragma unroll
      for (int i = 0; i < 4; ++i)
        af[i] = *(const short8*)&As[wr * 64 + i * 16 + (l & 15)]
                                  [kk * 32 + (l >> 4) * 8];
#pragma unroll
      for (int jn = 0; jn < 2 * JN; ++jn)
        bfv[jn] = *(const short8*)&Bs[wc * WCOL + jn * 16 + (l & 15)]
                                    [kk * 32 + (l >> 4) * 8];
#pragma unroll
      for (int i = 0; i < 4; ++i)
#pragma unroll
        for (int jn = 0; jn < 2 * JN; ++jn)
          acc[i][jn] = MFMA16(af[i], bfv[jn], acc[i][jn]);
    }
    __syncthreads();
  }

#pragma unroll
  for (int i = 0; i < 4; ++i) {
    int rbase = m0 + wr * 64 + i * 16 + (l >> 4) * 4;
#pragma unroll
    for (int jn = 0; jn < 2 * JN; ++jn) {
      int col = n0 + wc * WCOL + jn * 16 + (l & 15);
      float bv = bias[col];
#pragma unroll
      for (int r = 0; r < 4; ++r)
        st1(&C[(size_t)(rbase + r) * N + col], acc[i][jn][r] + bv);
    }
  }
}

// ---------------------------------------------------------------------------
// FALLBACK GEMM (reg-staged, fp32/bf16 template) — used if ws too small.
// ---------------------------------------------------------------------------
template <typename AT, typename OT>
__global__ __launch_bounds__(256, 2) void gemm_bt_bias(
    const AT* __restrict__ A, const float* __restrict__ B,
    const float* __restrict__ bias, OT* __restrict__ C, int M, int N, int K) {
  __shared__ bf16 As[128][64];
  __shared__ bf16 Bs[128][64];

  const int tid = threadIdx.x;
  const int w = tid >> 6, l = tid & 63;
  const int wr = w >> 1, wc = w & 1;
  const int m0 = blockIdx.y * 128, n0 = blockIdx.x * 128;

  f32x4 acc[4][4] = {};

  const int srow = tid >> 3;
  const int scol = (tid & 7) * 8;

  for (int kt = 0; kt < K; kt += 64) {
    short8 aReg[4], bReg[4];
#pragma unroll
    for (int p = 0; p < 4; ++p) {
      int row = p * 32 + srow;
      aReg[p] = ld8bf(A + (size_t)(m0 + row) * K + kt + scol);
      bReg[p] = ld8bf(B + (size_t)(n0 + row) * K + kt + scol);
    }
    __syncthreads();
#pragma unroll
    for (int p = 0; p < 4; ++p) {
      int row = p * 32 + srow;
      *(short8*)&As[row][scol] = aReg[p];
      *(short8*)&Bs[row][scol] = bReg[p];
    }
    __syncthreads();

#pragma unroll
    for (int kk = 0; kk < 2; ++kk) {
      short8 af[4], bfv[4];
#pragma unroll
      for (int i = 0; i < 4; ++i) {
        af[i]  = *(const short8*)&As[wr * 64 + i * 16 + (l & 15)]
                                   [kk * 32 + (l >> 4) * 8];
        bfv[i] = *(const short8*)&Bs[wc * 64 + i * 16 + (l & 15)]
                                   [kk * 32 + (l >> 4) * 8];
      }
#pragma unroll
      for (int i = 0; i < 4; ++i)
#pragma unroll
        for (int jn = 0; jn < 4; ++jn)
          acc[i][jn] = MFMA16(af[i], bfv[jn], acc[i][jn]);
    }
  }

#pragma unroll
  for (int i = 0; i < 4; ++i) {
    int rbase = m0 + wr * 64 + i * 16 + (l >> 4) * 4;
#pragma unroll
    for (int jn = 0; jn < 4; ++jn) {
      int col = n0 + wc * 64 + jn * 16 + (l & 15);
      float bv = bias[col];
#pragma unroll
      for (int r = 0; r < 4; ++r)
        st1(&C[(size_t)(rbase + r) * N + col], acc[i][jn][r] + bv);
    }
  }
}

// ---------------------------------------------------------------------------
// Flash attention, swapped-operand 32x32 MFMA, KVBLK=128
// + permlane32_swap P-exchange + cvt_pk bf16 packing (T12).
// ---------------------------------------------------------------------------
__global__ __launch_bounds__(256, 2) void attn_fwd(
    const bf16* __restrict__ qkv, bf16* __restrict__ attended) {
  const int S = 2048, D3 = 3072, D = 1024;
  // bijective XCD swizzle (512 = 8 x 64): each XCD owns 4 bh values entirely.
  const int flat = blockIdx.y * 16 + blockIdx.x;
  const int n = (flat & 7) * 64 + (flat >> 3);
  const int qt = n & 15, bh = n >> 4;
  const int b = bh >> 4, h = bh & 15;
  const int tid = threadIdx.x, w = tid >> 6, l = tid & 63;
  const int lo5 = l & 31, hi = l >> 5;

  __shared__ bf16 Klds[128][72];  // K[kv][e], row stride 144B
  __shared__ bf16 Vt[64][136];    // V^T[e][kv], row stride 272B

  const int q0w = qt * 128 + w * 32;

  short8 qf[4];
  {
    size_t qrow = (size_t)(b * S + q0w + lo5) * D3 + h * 64;
#pragma unroll
    for (int ks = 0; ks < 4; ++ks)
      qf[ks] = *(const short8*)&qkv[qrow + ks * 16 + hi * 8];
  }

  float m_raw = -1e30f, l_i = 0.f;
  f32x16 o0 = {}, o1 = {};

  const float Cs = 0.125f * 1.44269504088896340736f;  // hd^-0.5 * log2(e)

  const int srow = tid >> 2;
  const int scq = tid & 3;
  const size_t gb0 = (size_t)(b * S + srow) * D3 + h * 64 + scq * 16;
  const size_t HSTEP = (size_t)64 * D3;

  short8 k0, k1, k2, k3, v0, v1, v2, v3;
  {
    const bf16* g = qkv + gb0;
    k0 = *(const short8*)&g[1024];
    k1 = *(const short8*)&g[1024 + 8];
    v0 = *(const short8*)&g[2048];
    v1 = *(const short8*)&g[2048 + 8];
    const bf16* g2 = g + HSTEP;
    k2 = *(const short8*)&g2[1024];
    k3 = *(const short8*)&g2[1024 + 8];
    v2 = *(const short8*)&g2[2048];
    v3 = *(const short8*)&g2[2048 + 8];
  }

#define PACKP(G, SV)                                                           \
  {                                                                            \
    _Pragma("unroll") for (int tq = 0; tq < 4; ++tq) {                         \
      po[G][tq][0] = pk2((SV)[4 * tq], (SV)[4 * tq + 1]);                      \
      po[G][tq][1] = pk2((SV)[4 * tq + 2], (SV)[4 * tq + 3]);                  \
    }                                                                          \
  }

  for (int t = 0; t < 16; ++t) {
    __syncthreads();  // WAR
    *(short8*)&Klds[srow][scq * 16] = k0;
    *(short8*)&Klds[srow][scq * 16 + 8] = k1;
    *(short8*)&Klds[64 + srow][scq * 16] = k2;
    *(short8*)&Klds[64 + srow][scq * 16 + 8] = k3;
#pragma unroll
    for (int g = 0; g < 2; ++g) {
      int sI = scq * 2 + g;
      short8 ua = rotl8(g ? v1 : v0, sI);
      short8 ub = rotl8(g ? v3 : v2, sI);
#pragma unroll
      for (int j = 0; j < 8; ++j) {
        int jj = (j + sI) & 7;
        *(short*)&Vt[sI * 8 + jj][srow] = (short)ua[j];
        *(short*)&Vt[sI * 8 + jj][64 + srow] = (short)ub[j];
      }
    }
    __syncthreads();

    if (t + 1 < 16) {  // prefetch next K
      const bf16* g = qkv + gb0 + (size_t)(t + 1) * 2 * HSTEP;
      k0 = *(const short8*)&g[1024];
      k1 = *(const short8*)&g[1024 + 8];
      k2 = *(const short8*)&g[HSTEP + 1024];
      k3 = *(const short8*)&g[HSTEP + 1024 + 8];
    }

    // S^T = K @ Q^T
    f32x16 s0 = {}, s1 = {}, s2 = {}, s3 = {};
    __builtin_amdgcn_s_setprio(1);
#pragma unroll
    for (int ks = 0; ks < 4; ++ks) {
      short8 km0 = *(const short8*)&Klds[lo5][ks * 16 + hi * 8];
      short8 km1 = *(const short8*)&Klds[32 + lo5][ks * 16 + hi * 8];
      short8 km2 = *(const short8*)&Klds[64 + lo5][ks * 16 + hi * 8];
      short8 km3 = *(const short8*)&Klds[96 + lo5][ks * 16 + hi * 8];
      s0 = MFMA32(km0, qf[ks], s0);
      s1 = MFMA32(km1, qf[ks], s1);
      s2 = MFMA32(km2, qf[ks], s2);
      s3 = MFMA32(km3, qf[ks], s3);
    }
    __builtin_amdgcn_s_setprio(0);

    if (t + 1 < 16) {  // prefetch next V
      const bf16* g = qkv + gb0 + (size_t)(t + 1) * 2 * HSTEP;
      v0 = *(const short8*)&g[2048];
      v1 = *(const short8*)&g[2048 + 8];
      v2 = *(const short8*)&g[HSTEP + 2048];
      v3 = *(const short8*)&g[HSTEP + 2048 + 8];
    }

    // max over 128 kv (max3-fused trees)
    f32x16 tm;
#pragma unroll
    for (int r = 0; r < 16; ++r)
      tm[r] = fmaxf(fmaxf(fmaxf(s0[r], s1[r]), s2[r]), s3[r]);
    float a0 = fmaxf(fmaxf(tm[0], tm[1]), tm[2]);
    float a1 = fmaxf(fmaxf(tm[3], tm[4]), tm[5]);
    float a2 = fmaxf(fmaxf(tm[6], tm[7]), tm[8]);
    float a3 = fmaxf(fmaxf(tm[9], tm[10]), tm[11]);
    float a4 = fmaxf(fmaxf(tm[12], tm[13]), tm[14]);
    float b0v = fmaxf(fmaxf(a0, a1), a2);
    float b1v = fmaxf(fmaxf(a3, a4), tm[15]);
    float mx = fmaxf(b0v, b1v);
    mx = fmaxf(mx, __shfl_xor(mx, 32));

    bool deferred = __all((mx - m_raw) * Cs <= 8.0f);
    float mn, alpha;
    if (deferred) {
      mn = m_raw;
      alpha = 1.0f;
    } else {
      mn = fmaxf(m_raw, mx);
      alpha = __builtin_amdgcn_exp2f((m_raw - mn) * Cs);
      m_raw = mn;
    }
    float pc = mn * Cs;

#pragma unroll
    for (int r = 0; r < 16; ++r) {
      s0[r] = __builtin_amdgcn_exp2f(__builtin_fmaf(s0[r], Cs, -pc));
      s1[r] = __builtin_amdgcn_exp2f(__builtin_fmaf(s1[r], Cs, -pc));
      s2[r] = __builtin_amdgcn_exp2f(__builtin_fmaf(s2[r], Cs, -pc));
      s3[r] = __builtin_amdgcn_exp2f(__builtin_fmaf(s3[r], Cs, -pc));
    }
    f32x16 ts;
#pragma unroll
    for (int r = 0; r < 16; ++r)
      ts[r] = (s0[r] + s1[r]) + (s2[r] + s3[r]);
#pragma unroll
    for (int st = 8; st > 0; st >>= 1)
#pragma unroll
      for (int r = 0; r < st; ++r) ts[r] += ts[r + st];
    float sf = ts[0] + __shfl_xor(ts[0], 32);
    if (deferred) {
      l_i += sf;
    } else {
      l_i = l_i * alpha + sf;
      o0 *= alpha;
      o1 *= alpha;
    }

    // pack P quads (po[g][tq][hf]: kv = 32g + 8tq + 4hi + {0..3})
    unsigned po[4][4][2];
    PACKP(0, s0) PACKP(1, s1) PACKP(2, s2) PACKP(3, s3)

    // O^T += V^T @ P^T; B-fragment via permlane32_swap
    __builtin_amdgcn_s_setprio(1);
#pragma unroll
    for (int ks2 = 0; ks2 < 8; ++ks2) {
      const int g = ks2 >> 1, p = ks2 & 1;
      u32x2 ra = __builtin_amdgcn_permlane32_swap(po[g][2 * p][0],
                                                  po[g][2 * p + 1][0],
                                                  false, false);
      u32x2 rb = __builtin_amdgcn_permlane32_swap(po[g][2 * p][1],
                                                  po[g][2 * p + 1][1],
                                                  false, false);
      u32x4 fw;
      fw[0] = ra[0];
      fw[1] = rb[0];
      fw[2] = ra[1];
      fw[3] = rb[1];
      short8 pf = __builtin_bit_cast(short8, fw);
      short8 va0 = *(const short8*)&Vt[lo5][ks2 * 16 + hi * 8];
      short8 va1 = *(const short8*)&Vt[32 + lo5][ks2 * 16 + hi * 8];
      o0 = MFMA32(va0, pf, o0);
      o1 = MFMA32(va1, pf, o1);
    }
    __builtin_amdgcn_s_setprio(0);
  }

  float inv = 1.0f / l_i;
  size_t orow = (size_t)(b * S + q0w + lo5) * D + h * 64;
#pragma unroll
  for (int t = 0; t < 4; ++t) {
    u32x2 w0, w1;
    w0[0] = pk2(o0[4 * t] * inv, o0[4 * t + 1] * inv);
    w0[1] = pk2(o0[4 * t + 2] * inv, o0[4 * t + 3] * inv);
    w1[0] = pk2(o1[4 * t] * inv, o1[4 * t + 1] * inv);
    w1[1] = pk2(o1[4 * t + 2] * inv, o1[4 * t + 3] * inv);
    *(u32x2*)&attended[orow + 8 * t + 4 * hi] = w0;
    *(u32x2*)&attended[orow + 32 + 8 * t + 4 * hi] = w1;
  }
}

// ---------------------------------------------------------------------------
extern "C" void kernel_launch(void* const* d_in, const int* in_sizes, int n_in,
                              void* d_out, int out_size, void* d_ws,
                              size_t ws_size, hipStream_t stream) {
  const float* x     = (const float*)d_in[0];   // [2,2048,1024] fp32
  const float* w_qkv = (const float*)d_in[1];   // [3072,1024]   fp32
  const float* b_qkv = (const float*)d_in[2];   // [3072]        fp32
  const float* w_out = (const float*)d_in[3];   // [1024,1024]   fp32
  const float* b_out = (const float*)d_in[4];   // [1024]        fp32
  float* out = (float*)d_out;                   // [2,2048,1024] fp32

  const int BS = 4096;   // B*S
  const int D = 1024, D3 = 3072;
  const int NX = BS * D, NWQ = D3 * D, NWO = D * D;

  bf16* qkv = (bf16*)d_ws;                       // [4096][3072] 25.2 MB
  bf16* att = qkv + (size_t)BS * D3;             // [4096][1024]  8.4 MB

  const size_t NEED = ((size_t)BS * D3 + (size_t)BS * D + (size_t)D3 * D +
                       (size_t)D * D) * sizeof(bf16);

  if (ws_size >= NEED) {
    bf16* xb  = att;                             // overlaid with att
    bf16* wqb = xb + (size_t)NX;
    bf16* wob = wqb + (size_t)NWQ;

    int ncvt = (NX + NWQ + NWO) / 8;
    cvt3<<<(ncvt + 255) / 256, 256, 0, stream>>>(x, xb, NX, w_qkv, wqb, NWQ,
                                                 w_out, wob, NWO);
    gemm_lds_bias<128, bf16><<<dim3(D3 / 128, BS / 128), 256, 0, stream>>>(
        xb, wqb, b_qkv, qkv, BS, D3, D);
    attn_fwd<<<dim3(16, 32), 256, 0, stream>>>(qkv, att);  // clobbers xb/wqb
    gemm_lds_bias<64, float><<<dim3(D / 64, BS / 128), 256, 0, stream>>>(
        att, wob, b_out, out, BS, D, D);
  } else {
    gemm_bt_bias<float, bf16><<<dim3(D3 / 128, BS / 128), 256, 0, stream>>>(
        x, w_qkv, b_qkv, qkv, BS, D3, D);
    attn_fwd<<<dim3(16, 32), 256, 0, stream>>>(qkv, att);
    gemm_bt_bias<bf16, float><<<dim3(D / 128, BS / 128), 256, 0, stream>>>(
        att, w_out, b_out, out, BS, D, D);
  }
}